// Round 1
// 113.271 us; speedup vs baseline: 1.0017x; 1.0017x over previous
//
#include <hip/hip_runtime.h>
#include <hip/hip_bf16.h>
#include <math.h>

// S5 SSM layer. B_SZ=16, L=1024, H=256, P=256.
// 4 dispatches (R11: dedupe u / XS reads, carry-table kernel):
//   k_prep     : W1T, W2T, PW (lambda-power table)
//   k_g1scan   : per-chunk GEMM1 (BM=32, BN=512 full width) -> LDS X -> local scan -> XS + CEND
//   k_carry    : full carry table via one serial pass per (batch, p)  [replaces per-block prologue]
//   k_gemm2fix : GEMM2 (BM=32, BN=256 full width) with fixup-in-staging + D*u
#define BB     16
#define LSEQ   1024
#define HH     256
#define PP     256
#define MROWS  (BB*LSEQ)     // 16384
#define LC     32
#define NC     (LSEQ/LC)     // 32
#define NCHUNK (BB*NC)       // 512

// workspace byte offsets
#define OFF_W1T  0u          // [512][256] bf16: row 2p=Re(B_bar[p][.]), 2p+1=Im
#define OFF_W2T  262144u     // [256][512] bf16: row h, k=2p -> 2*C_re, 2p+1 -> -2*C_im
#define OFF_PW   524288u     // [33][256] float2: lambda_bar^t
#define OFF_CEND 655360u     // [512][256] float2 chunk-end local states (1 MB)
#define OFF_CARR 1703936u    // [512][256] float2 carry entering each chunk (1 MB)
#define OFF_XS   2752512u    // [16384][512] bf16 x_local (col 2p=re, 2p+1=im)
// total ~19.5 MB

typedef __attribute__((ext_vector_type(8))) short short8;
typedef __attribute__((ext_vector_type(4))) float floatx4;

__device__ __forceinline__ float bf2f(unsigned hs) {
    union { unsigned u; float f; } v; v.u = hs << 16; return v.f;
}
__device__ __forceinline__ unsigned short f2bs(float f) {
    __hip_bfloat16 h = __float2bfloat16(f);
    union { __hip_bfloat16 h; unsigned short s; } v; v.h = h; return v.s;
}
__device__ __forceinline__ unsigned packbf(float r, float i) {
    return (unsigned)f2bs(r) | ((unsigned)f2bs(i) << 16);
}
__device__ __forceinline__ void async16(const void* g, void* l) {
    __builtin_amdgcn_global_load_lds(
        (const __attribute__((address_space(1))) unsigned*)g,
        (__attribute__((address_space(3))) unsigned*)l, 16, 0, 0);
}
__device__ __forceinline__ float2 lam_pow(float lr, float li, float dtt) {
    float m = expf(lr * dtt);
    return make_float2(m * cosf(li * dtt), m * sinf(li * dtt));
}

// ---------------- prep: W1T/PW (blocks 0..255) and W2T (256..511) ----------------
__global__ void k_prep(const float* __restrict__ Bm, const float* __restrict__ Cm,
                       const float* __restrict__ Lr, const float* __restrict__ Li,
                       const float* __restrict__ ls, char* __restrict__ ws) {
    int blk = blockIdx.x, t = threadIdx.x;
    if (blk < 256) {
        int p = blk, h = t;
        float lr = Lr[p], li = Li[p];
        float dt = expf(ls[p]);
        float2 lam = lam_pow(lr, li, dt);
        float den = lr * lr + li * li;
        float nr = lam.x - 1.0f, ni = lam.y;
        float cr = (nr * lr + ni * li) / den;       // (lam_bar-1)/Lambda
        float ci = (ni * lr - nr * li) / den;
        float br = Bm[(p * HH + h) * 2 + 0];
        float bi = Bm[(p * HH + h) * 2 + 1];
        unsigned short* w1 = (unsigned short*)(ws + OFF_W1T);
        w1[(2 * p) * 256 + h]     = f2bs(cr * br - ci * bi);
        w1[(2 * p + 1) * 256 + h] = f2bs(cr * bi + ci * br);
        if (t <= 32)   // lambda power table pw[t][p]
            ((float2*)(ws + OFF_PW))[t * 256 + p] = lam_pow(lr, li, dt * (float)t);
    } else {
        int h = blk - 256, p = t;
        float c_r = Cm[(h * PP + p) * 2 + 0];
        float c_i = Cm[(h * PP + p) * 2 + 1];
        ((unsigned*)(ws + OFF_W2T))[h * 256 + p] = packbf(2.0f * c_r, -2.0f * c_i);
    }
}

// ---------------- GEMM1 + local chunk scan; grid 512 = one block per chunk ----
// 512 threads (8 waves, 64-col slice each). BM=32, BN=512 (full width), BK=64 two-panel.
// LDS: A [2][32][32]bf16 (4KB) + B [2][512][32]bf16 (64KB) = 68KB, X aliased on top.
#define XSTRD 514            // dword stride of LDS X rows (4*514 mod 128B -> q-groups spread banks)
#define XSTRS 1028           // short stride
__global__ __launch_bounds__(512, 4) void k_g1scan(
        const float* __restrict__ u, const float* __restrict__ Lr,
        const float* __restrict__ Li, const float* __restrict__ ls,
        char* __restrict__ ws) {
    extern __shared__ char smem[];
    char* Asb = smem;                            // [2][32][32] bf16 (2 KB/panel)
    char* Bsb = smem + 4096;                     // [2][512][32] bf16 (32 KB/panel)
    unsigned short* X = (unsigned short*)smem;   // [32][XSTRS] after GEMM (~66 KB)
    unsigned* X32 = (unsigned*)smem;             // stride XSTRD
    const unsigned short* W1 = (const unsigned short*)(ws + OFF_W1T);
    const int tid = threadIdx.x, bc = blockIdx.x;   // bc = global chunk id
    const int m0 = bc * LC;
    const int wave = tid >> 6, lane = tid & 63;
    const int q = lane >> 4, rr = lane & 15;
    const int c4 = lane & 3, r4 = lane >> 2;

    floatx4 acc[2][4];
    #pragma unroll
    for (int i = 0; i < 2; ++i)
        #pragma unroll
        for (int j = 0; j < 4; ++j) acc[i][j] = (floatx4)0.0f;

    const int arow = tid >> 4, acol4 = (tid & 15) * 4;   // A-stage: 1 float4/thread
    for (int k0 = 0; k0 < 256; k0 += 64) {
        __syncthreads();
        {   // A panel: u 32x64 fp32 -> bf16 (read ONCE per chunk now)
            float4 v = *(const float4*)(u + (size_t)(m0 + arow) * 256 + k0 + acol4);
            *(uint2*)(Asb + (acol4 >> 5) * 2048 + arow * 64 + (acol4 & 31) * 2) =
                make_uint2(packbf(v.x, v.y), packbf(v.z, v.w));
        }
        #pragma unroll
        for (int t = 0; t < 8; ++t) {   // B: 512 rows x 2 panels via DMA (64 instrs)
            int idx = t * 8 + wave;     // 0..63
            int pan = idx & 1, rowg = idx >> 1;
            int row = rowg * 16 + r4;
            async16(W1 + (size_t)row * 256 + k0 + pan * 32 + c4 * 8,
                    Bsb + pan * 32768 + row * 64 + c4 * 16);
        }
        __syncthreads();
        #pragma unroll
        for (int ks = 0; ks < 2; ++ks) {
            short8 a0 = *(const short8*)(Asb + ks * 2048 + rr * 64 + q * 16);
            short8 a1 = *(const short8*)(Asb + ks * 2048 + (16 + rr) * 64 + q * 16);
            #pragma unroll
            for (int j = 0; j < 4; ++j) {
                short8 b = *(const short8*)(Bsb + ks * 32768 +
                                            (wave * 64 + j * 16 + rr) * 64 + q * 16);
                acc[0][j] = __builtin_amdgcn_mfma_f32_16x16x32_bf16(a0, b, acc[0][j], 0, 0, 0);
                acc[1][j] = __builtin_amdgcn_mfma_f32_16x16x32_bf16(a1, b, acc[1][j], 0, 0, 0);
            }
        }
    }
    __syncthreads();
    // dump Bu tile (32 x 512) into padded LDS X
    #pragma unroll
    for (int i = 0; i < 2; ++i)
        #pragma unroll
        for (int j = 0; j < 4; ++j)
            #pragma unroll
            for (int r0 = 0; r0 < 4; ++r0)
                X[(i * 16 + q * 4 + r0) * XSTRS + wave * 64 + j * 16 + rr] =
                    f2bs(acc[i][j][r0]);
    __syncthreads();

    // local chunk scan: 256 units (all channel pairs), waves 0-3
    if (tid < 256) {
        const int pq = tid;
        const float2 lam = lam_pow(Lr[pq], Li[pq], expf(ls[pq]));
        unsigned* xs32 = (unsigned*)(ws + OFF_XS);
        float xr = 0.0f, xi = 0.0f;
        #pragma unroll
        for (int j = 0; j < LC; ++j) {
            unsigned cv = X32[j * XSTRD + pq];
            float br = bf2f(cv & 0xffffu), bi = bf2f(cv >> 16);
            float nr = fmaf(lam.x, xr, fmaf(-lam.y, xi, br));
            float ni = fmaf(lam.x, xi, fmaf(lam.y, xr, bi));
            xr = nr; xi = ni;
            xs32[(size_t)(m0 + j) * 256 + pq] = packbf(xr, xi);
        }
        ((float2*)(ws + OFF_CEND))[(size_t)bc * 256 + pq] = make_float2(xr, xi);
    }
}

// ---------------- carry table: one serial pass per (batch, p) --------------------
// carry entering chunk c:  carr_0 = 0;  carr_c = g*carr_{c-1} + e_{c-1},  g = lam^LC.
// 16 blocks x 256 threads; loads coalesced, fixed trip count (fully pipelineable).
__global__ void k_carry(const float* __restrict__ Lr, const float* __restrict__ Li,
                        const float* __restrict__ ls, char* __restrict__ ws) {
    const int b = blockIdx.x, p = threadIdx.x;
    const float2* cend = (const float2*)(ws + OFF_CEND);
    float2* carr = (float2*)(ws + OFF_CARR);
    const float2 g = lam_pow(Lr[p], Li[p], expf(ls[p]) * (float)LC);
    float sr = 0.0f, si = 0.0f;
    #pragma unroll
    for (int c = 0; c < NC; ++c) {
        size_t idx = (size_t)(b * NC + c) * 256 + p;
        carr[idx] = make_float2(sr, si);
        float2 e = cend[idx];
        float nr = fmaf(g.x, sr, fmaf(-g.y, si, e.x));
        float ni = fmaf(g.x, si, fmaf(g.y, sr, e.y));
        sr = nr; si = ni;
    }
}

// ---------------- GEMM2: carry-table load + fixup-in-staging + D*u ---------------
// out = (x_local + lam^{j+1}*carry) @ W2T^T + D*u. BM=32, BN=256 (full width),
// grid 512 (one block per chunk), 256 threads (4 waves, 64-col slice each), BK=64.
__global__ __launch_bounds__(256, 4) void k_gemm2fix(
        const char* __restrict__ ws_c, const float* __restrict__ D,
        const float* __restrict__ u, float* __restrict__ out) {
    __shared__ char Asb[4096];          // [2][32][32] bf16
    __shared__ char Bsb[32768];         // [2][256][32] bf16
    __shared__ float2 carrs[256];       // this chunk's carry
    const unsigned short* W2 = (const unsigned short*)(ws_c + OFF_W2T);
    const unsigned* xs32 = (const unsigned*)(ws_c + OFF_XS);
    const float2* pw = (const float2*)(ws_c + OFF_PW);
    const float2* carr = (const float2*)(ws_c + OFF_CARR);

    const int tid = threadIdx.x;
    const int wave = tid >> 6, lane = tid & 63;
    const int q = lane >> 4, rr = lane & 15;
    const int c4 = lane & 3, r4 = lane >> 2;
    const int m0 = blockIdx.x * LC;     // chunk id = blockIdx.x

    carrs[tid] = carr[(size_t)blockIdx.x * 256 + tid];   // one coalesced 2KB load

    floatx4 acc[2][4];
    #pragma unroll
    for (int i = 0; i < 2; ++i)
        #pragma unroll
        for (int j = 0; j < 4; ++j) acc[i][j] = (floatx4)0.0f;

    const int row = tid >> 3, qd = tid & 7;    // staging: 4 pairs/thread/iter
    const int grow = m0 + row;
    const int jj = (grow & (LC - 1)) + 1;

    for (int k0 = 0; k0 < 512; k0 += 64) {
        __syncthreads();   // publishes carrs on first iteration
        {
            int p0 = (k0 >> 1) + qd * 4;
            uint4 xa = *(const uint4*)(xs32 + (size_t)grow * 256 + p0);
            unsigned xv[4] = {xa.x, xa.y, xa.z, xa.w};
            const float2* pwp = pw + (size_t)jj * 256 + p0;
            unsigned o[4];
            #pragma unroll
            for (int e = 0; e < 4; ++e) {
                float2 pwv = pwp[e];
                float2 cav = carrs[p0 + e];
                float fr = pwv.x * cav.x - pwv.y * cav.y;
                float fi = pwv.x * cav.y + pwv.y * cav.x;
                o[e] = packbf(bf2f(xv[e] & 0xffffu) + fr, bf2f(xv[e] >> 16) + fi);
            }
            char* dst = Asb + (qd >> 2) * 2048 + row * 64 + (qd & 3) * 16;
            *(uint4*)dst = make_uint4(o[0], o[1], o[2], o[3]);
        }
        #pragma unroll
        for (int t = 0; t < 8; ++t) {          // Bs: 256 rows x 2 panels (32 instrs)
            int idx = t * 4 + wave;            // 0..31
            int pan = idx & 1, rowg = idx >> 1;
            int rw = rowg * 16 + r4;
            async16(W2 + (size_t)rw * 512 + k0 + pan * 32 + c4 * 8,
                    Bsb + pan * 16384 + rw * 64 + c4 * 16);
        }
        __syncthreads();
        #pragma unroll
        for (int ks = 0; ks < 2; ++ks) {
            short8 a[2], bfr[4];
            #pragma unroll
            for (int i = 0; i < 2; ++i)
                a[i] = *(const short8*)(Asb + ks * 2048 + (i * 16 + rr) * 64 + q * 16);
            #pragma unroll
            for (int j = 0; j < 4; ++j)
                bfr[j] = *(const short8*)(Bsb + ks * 16384 +
                                          (wave * 64 + j * 16 + rr) * 64 + q * 16);
            #pragma unroll
            for (int i = 0; i < 2; ++i)
                #pragma unroll
                for (int j = 0; j < 4; ++j)
                    acc[i][j] = __builtin_amdgcn_mfma_f32_16x16x32_bf16(a[i], bfr[j], acc[i][j], 0, 0, 0);
        }
    }

    #pragma unroll
    for (int i = 0; i < 2; ++i) {
        int mbase = m0 + i * 16 + q * 4;
        #pragma unroll
        for (int j = 0; j < 4; ++j) {
            int col = wave * 64 + j * 16 + rr;
            #pragma unroll
            for (int r0 = 0; r0 < 4; ++r0) {
                int rw = mbase + r0;
                size_t gi = (size_t)rw * 256 + col;
                out[gi] = acc[i][j][r0] + D[col] * u[gi];
            }
        }
    }
}

extern "C" void kernel_launch(void* const* d_in, const int* in_sizes, int n_in,
                              void* d_out, int out_size, void* d_ws, size_t ws_size,
                              hipStream_t stream) {
    const float* u  = (const float*)d_in[0];
    const float* Lr = (const float*)d_in[1];
    const float* Li = (const float*)d_in[2];
    const float* Bm = (const float*)d_in[3];
    const float* Cm = (const float*)d_in[4];
    const float* D  = (const float*)d_in[5];
    const float* ls = (const float*)d_in[6];
    float* out = (float*)d_out;
    char* ws = (char*)d_ws;

    k_prep<<<512, 256, 0, stream>>>(Bm, Cm, Lr, Li, ls, ws);
    k_g1scan<<<NCHUNK, 512, 69632, stream>>>(u, Lr, Li, ls, ws);
    k_carry<<<BB, 256, 0, stream>>>(Lr, Li, ls, ws);
    k_gemm2fix<<<NCHUNK, 256, 0, stream>>>(ws, D, u, out);
}